// Round 6
// baseline (1152.901 us; speedup 1.0000x reference)
//
#include <hip/hip_runtime.h>
#include <hip/hip_bf16.h>
#include <stdint.h>

#define NN 100000
#define NFEATD 256
#define NHIDD 512
#define NCLASSD 256

typedef short bf16x8 __attribute__((ext_vector_type(8)));
typedef float f32x4 __attribute__((ext_vector_type(4)));
typedef float f32x2 __attribute__((ext_vector_type(2)));

__device__ __forceinline__ float bf2f(uint32_t u) {
    union { uint32_t i; float f; } v; v.i = u << 16; return v.f;
}
__device__ __forceinline__ ushort f2bf(float f) {
    uint32_t x = __float_as_uint(f);
    uint32_t r = (x + 0x7FFF + ((x >> 16) & 1)) >> 16;
    return (ushort)r;
}

// ---------------- small utility kernels ----------------
__global__ void zero_i32(int* __restrict__ p, int n) {
    int i = blockIdx.x * 256 + threadIdx.x;
    if (i < n) p[i] = 0;
}

__global__ void count_deg(const int* __restrict__ dst, int* __restrict__ deg, int nE) {
    int e = blockIdx.x * 256 + threadIdx.x;
    if (e < nE) atomicAdd(&deg[dst[e]], 1);
}

// single-block exclusive scan over n ints, 1024 threads
__global__ __launch_bounds__(1024) void scan_excl(const int* __restrict__ deg,
                                                  int* __restrict__ off, int n) {
    __shared__ int wsum[16];
    __shared__ int carry_s;
    const int tid = threadIdx.x;
    const int lane = tid & 63, wv = tid >> 6;
    if (tid == 0) carry_s = 0;
    __syncthreads();
    for (int base = 0; base < n; base += 1024) {
        int i = base + tid;
        int v = (i < n) ? deg[i] : 0;
        int x = v;
#pragma unroll
        for (int d = 1; d < 64; d <<= 1) {
            int y = __shfl_up(x, d, 64);
            if (lane >= d) x += y;
        }
        if (lane == 63) wsum[wv] = x;
        __syncthreads();
        if (wv == 0 && lane < 16) {
            int s = wsum[lane];
#pragma unroll
            for (int d = 1; d < 16; d <<= 1) {
                int y = __shfl_up(s, d, 16);
                if (lane >= d) s += y;
            }
            wsum[lane] = s;
        }
        __syncthreads();
        int carry = carry_s;
        int wprefix = (wv == 0) ? 0 : wsum[wv - 1];
        if (i < n) off[i] = carry + wprefix + x - v;
        __syncthreads();
        if (tid == 0) carry_s = carry + wsum[15];
        __syncthreads();
    }
    if (tid == 0) off[n] = carry_s;
}

__global__ void fill_csr(const int* __restrict__ src, const int* __restrict__ dst,
                         const int* __restrict__ off, int* __restrict__ cursor,
                         int* __restrict__ csr, int nE) {
    int e = blockIdx.x * 256 + threadIdx.x;
    if (e >= nE) return;
    int d = dst[e];
    int p = off[d] + atomicAdd(&cursor[d], 1);
    csr[p] = src[e];
}

// ---------------- weight prep: all four [K][N] f32 -> [N][K] bf16 in ONE launch ------
__global__ void prep_w4(const float* __restrict__ W1a, const float* __restrict__ W1b,
                        const float* __restrict__ W2a, const float* __restrict__ W2b,
                        ushort* __restrict__ Wt1a, ushort* __restrict__ Wt1b,
                        ushort* __restrict__ Wt2a, ushort* __restrict__ Wt2b) {
    int idx = blockIdx.x * 256 + threadIdx.x;
    // segment sizes: 256*512, 512*512, 512*512, 512*256
    if (idx < 131072) {                       // W1a: K=256, N=512
        int k = idx >> 9, n = idx & 511;
        Wt1a[n * 256 + k] = f2bf(W1a[idx]);
    } else if (idx < 131072 + 262144) {       // W1b: K=512, N=512
        int i = idx - 131072;
        int k = i >> 9, n = i & 511;
        Wt1b[n * 512 + k] = f2bf(W1b[i]);
    } else if (idx < 131072 + 524288) {       // W2a: K=512, N=512
        int i = idx - (131072 + 262144);
        int k = i >> 9, n = i & 511;
        Wt2a[n * 512 + k] = f2bf(W2a[i]);
    } else if (idx < 131072 + 524288 + 131072) {  // W2b: K=512, N=256
        int i = idx - (131072 + 524288);
        int k = i >> 8, n = i & 255;
        Wt2b[n * 512 + k] = f2bf(W2b[i]);
    }
}

// f32 -> fp8 e4m3 cast, 8 elems/thread
__global__ void cast_f32_fp8(const float* __restrict__ a, uint8_t* __restrict__ o, int n) {
    int i = (blockIdx.x * 256 + threadIdx.x) * 8;
    if (i >= n) return;
    float4 v0 = *(const float4*)(a + i);
    float4 v1 = *(const float4*)(a + i + 4);
    int lo = __builtin_amdgcn_cvt_pk_fp8_f32(v0.x, v0.y, 0, false);
    lo = __builtin_amdgcn_cvt_pk_fp8_f32(v0.z, v0.w, lo, true);
    int hi = __builtin_amdgcn_cvt_pk_fp8_f32(v1.x, v1.y, 0, false);
    hi = __builtin_amdgcn_cvt_pk_fp8_f32(v1.z, v1.w, hi, true);
    uint2 r; r.x = (uint32_t)lo; r.y = (uint32_t)hi;
    *(uint2*)(o + i) = r;
}

// decode 4 fp8 (one uint32) -> packed-f32 accumulate (v_pk_add_f32)
__device__ __forceinline__ void accp(uint32_t p, f32x2& lo, f32x2& hi) {
    lo += __builtin_amdgcn_cvt_pk_f32_fp8((int)p, false);
    hi += __builtin_amdgcn_cvt_pk_f32_fp8((int)p, true);
}

// ---------------- CSR gather: agg[n] = (1+eps)*x[n] + sum_{s in nbr(n)} x[s] ---------
// At its structural floor: compulsory L2-fill = table(51.2MB) x 8 XCDs ~= 402 MB (measured).
// one wave per node, F=256 fp8 input (uint/lane = 4 fp8), unroll 8, packed-f32 acc
__global__ void gather256f8(const uint8_t* __restrict__ X8, const int* __restrict__ off,
                            const int* __restrict__ csr, const float* __restrict__ eps,
                            ushort* __restrict__ out) {
    int node = (blockIdx.x * 256 + threadIdx.x) >> 6;
    if (node >= NN) return;
    int lane = threadIdx.x & 63;
    float sc = 1.0f + *eps;
    f32x2 scv = {sc, sc};
    const uint32_t* X1 = (const uint32_t*)X8;  // 64 uints per row
    f32x2 lo = {0.f, 0.f}, hi = {0.f, 0.f};
    {
        uint32_t p = X1[(size_t)node * 64 + lane];
        lo = scv * __builtin_amdgcn_cvt_pk_f32_fp8((int)p, false);
        hi = scv * __builtin_amdgcn_cvt_pk_f32_fp8((int)p, true);
    }
    int e = off[node], e1 = off[node + 1];
    for (; e + 7 < e1; e += 8) {
        uint32_t p[8];
#pragma unroll
        for (int t = 0; t < 8; ++t) p[t] = X1[(size_t)csr[e + t] * 64 + lane];
#pragma unroll
        for (int t = 0; t < 8; ++t) accp(p[t], lo, hi);
    }
    for (; e < e1; ++e)
        accp(X1[(size_t)csr[e] * 64 + lane], lo, hi);
    uint2 r;
    r.x = (uint32_t)f2bf(lo[0]) | ((uint32_t)f2bf(lo[1]) << 16);
    r.y = (uint32_t)f2bf(hi[0]) | ((uint32_t)f2bf(hi[1]) << 16);
    *(uint2*)(out + (size_t)node * 256 + lane * 4) = r;
}

// one wave per node, F=512 fp8 input (uint2/lane = 8 fp8), unroll 8, packed-f32 acc
__global__ void gather512f8(const uint8_t* __restrict__ H8, const int* __restrict__ off,
                            const int* __restrict__ csr, const float* __restrict__ eps,
                            ushort* __restrict__ out) {
    int node = (blockIdx.x * 256 + threadIdx.x) >> 6;
    if (node >= NN) return;
    int lane = threadIdx.x & 63;
    float sc = 1.0f + *eps;
    f32x2 scv = {sc, sc};
    const uint2* H2 = (const uint2*)H8;  // 64 uint2 per row
    f32x2 l0 = {0.f, 0.f}, h0 = {0.f, 0.f}, l1 = {0.f, 0.f}, h1 = {0.f, 0.f};
    {
        uint2 p = H2[(size_t)node * 64 + lane];
        l0 = scv * __builtin_amdgcn_cvt_pk_f32_fp8((int)p.x, false);
        h0 = scv * __builtin_amdgcn_cvt_pk_f32_fp8((int)p.x, true);
        l1 = scv * __builtin_amdgcn_cvt_pk_f32_fp8((int)p.y, false);
        h1 = scv * __builtin_amdgcn_cvt_pk_f32_fp8((int)p.y, true);
    }
    int e = off[node], e1 = off[node + 1];
    for (; e + 7 < e1; e += 8) {
        uint2 p[8];
#pragma unroll
        for (int t = 0; t < 8; ++t) p[t] = H2[(size_t)csr[e + t] * 64 + lane];
#pragma unroll
        for (int t = 0; t < 8; ++t) {
            accp(p[t].x, l0, h0);
            accp(p[t].y, l1, h1);
        }
    }
    for (; e < e1; ++e) {
        uint2 p = H2[(size_t)csr[e] * 64 + lane];
        accp(p.x, l0, h0);
        accp(p.y, l1, h1);
    }
    uint4 r;
    r.x = (uint32_t)f2bf(l0[0]) | ((uint32_t)f2bf(l0[1]) << 16);
    r.y = (uint32_t)f2bf(h0[0]) | ((uint32_t)f2bf(h0[1]) << 16);
    r.z = (uint32_t)f2bf(l1[0]) | ((uint32_t)f2bf(l1[1]) << 16);
    r.w = (uint32_t)f2bf(h1[0]) | ((uint32_t)f2bf(h1[1]) << 16);
    *(uint4*)(out + (size_t)node * 512 + lane * 8) = r;
}

// ---------------- GEMM v4: 128x128 tile, 4 waves, A-only LDS dbuf, B direct L2->VGPR --
// C[M,N] = A[M,K](bf16) * Bt[N,K](bf16)^T + bias, opt relu
// Weights (B) are <=512 KB -> fully L2-resident (read by all 782 row-blocks). So skip
// the B LDS round-trip: load B fragments global->reg (same address formula as staging),
// ping-pong double-buffer bA/bB (statically indexed, unroll-2 over chunk pairs).
// A stays in 2-slot LDS dbuf (16 KB total) via global_load_lds. One barrier per chunk;
// next-chunk A-stage + B-loads issue BEFORE ds_read+MFMA (T3 overlap), drain at barrier.
// VGPR ~120 (acc 64 + af 16 + bA/bB 32) -> __launch_bounds__(256,4) -> 4 blocks/CU.
// Operand-swapped MFMA (M on lane&15, N on quad*4+reg) -> vectorized stores. Col-inner
// grid for A-panel L3 reuse (proven FETCH 204->104 MB).

__device__ __forceinline__ void stage_a256(const ushort* __restrict__ A, int K, int row0,
                                           int kc, ushort* dst, int tid, int Mm1) {
#pragma unroll
    for (int i = 0; i < 2; ++i) {
        int u = i * 256 + tid;                 // 512 x 16B chunks: 128 rows x 4 col-blocks
        int r = u >> 2, c = u & 3;
        int gr = row0 + r; if (gr > Mm1) gr = Mm1;
        const ushort* gp = A + (size_t)gr * K + kc + c * 8;
        __builtin_amdgcn_global_load_lds((const __attribute__((address_space(1))) void*)gp,
            (__attribute__((address_space(3))) void*)(dst + u * 8), 16, 0, 0);
    }
}

__global__ __launch_bounds__(256, 4) void gemm_bt(
    const ushort* __restrict__ A, const ushort* __restrict__ Bt,
    const float* __restrict__ bias, float* __restrict__ outf,
    uint8_t* __restrict__ out8, ushort* __restrict__ outb,
    int M, int N, int K, int relu)
{
    __shared__ ushort As[2][4096];      // two 128x32 bf16 slots, 16 KB
    const int tid = threadIdx.x;
    const int wave = tid >> 6, lane = tid & 63;
    const int quad = lane >> 4, lrow = lane & 15;
    const int wr = wave >> 1, wc = wave & 1;       // 2x2 waves, 64x64 out each
    const int row0 = blockIdx.y * 128, col0 = blockIdx.x * 128;
    const int NC = K >> 5;                          // even for K=256/512

    f32x4 acc[4][4] = {};
    bf16x8 bA[4], bB[4], af[4];

    // per-lane B base: row = col0 + wc*64 + lrow (+ n*16), col = quad*8 (+ k)
    const ushort* bbase = Bt + (size_t)(col0 + wc * 64 + lrow) * K + quad * 8;

    // prologue: stage A chunk 0; load B chunk 0 into bA; drain
    stage_a256(A, K, row0, 0, As[0], tid, M - 1);
#pragma unroll
    for (int n = 0; n < 4; ++n) bA[n] = *(const bf16x8*)(bbase + n * 16 * K);
    __syncthreads();

    for (int t = 0; t < NC; t += 2) {
        // ---- even chunk t: compute from As[0]/bA, prefetch t+1 into As[1]/bB ----
        {
            int kn = (t + 1) << 5;                  // t+1 < NC always (NC even)
            stage_a256(A, K, row0, kn, As[1], tid, M - 1);
#pragma unroll
            for (int n = 0; n < 4; ++n) bB[n] = *(const bf16x8*)(bbase + n * 16 * K + kn);
        }
#pragma unroll
        for (int m = 0; m < 4; ++m)
            af[m] = *(const bf16x8*)(As[0] + (wr * 64 + m * 16 + lrow) * 32 + quad * 8);
        __builtin_amdgcn_s_setprio(1);
#pragma unroll
        for (int m = 0; m < 4; ++m)
#pragma unroll
            for (int n = 0; n < 4; ++n)
                acc[m][n] = __builtin_amdgcn_mfma_f32_16x16x32_bf16(bA[n], af[m], acc[m][n], 0, 0, 0);
        __builtin_amdgcn_s_setprio(0);
        __syncthreads();                            // drains t+1 loads; WAR fence

        // ---- odd chunk t+1: compute from As[1]/bB, prefetch t+2 into As[0]/bA ----
        if (t + 2 < NC) {
            int kn = (t + 2) << 5;
            stage_a256(A, K, row0, kn, As[0], tid, M - 1);
#pragma unroll
            for (int n = 0; n < 4; ++n) bA[n] = *(const bf16x8*)(bbase + n * 16 * K + kn);
        }
#pragma unroll
        for (int m = 0; m < 4; ++m)
            af[m] = *(const bf16x8*)(As[1] + (wr * 64 + m * 16 + lrow) * 32 + quad * 8);
        __builtin_amdgcn_s_setprio(1);
#pragma unroll
        for (int m = 0; m < 4; ++m)
#pragma unroll
            for (int n = 0; n < 4; ++n)
                acc[m][n] = __builtin_amdgcn_mfma_f32_16x16x32_bf16(bB[n], af[m], acc[m][n], 0, 0, 0);
        __builtin_amdgcn_s_setprio(0);
        __syncthreads();
    }

    // epilogue: swapped-operand C/D layout: M-row = lane&15, N-col = quad*4 + reg
#pragma unroll
    for (int m = 0; m < 4; ++m) {
        int rr = row0 + wr * 64 + m * 16 + lrow;
        if (rr < M) {
#pragma unroll
            for (int n = 0; n < 4; ++n) {
                int c = col0 + wc * 64 + n * 16 + quad * 4;
                float4 bv = *(const float4*)(bias + c);
                float v0 = acc[m][n][0] + bv.x;
                float v1 = acc[m][n][1] + bv.y;
                float v2 = acc[m][n][2] + bv.z;
                float v3 = acc[m][n][3] + bv.w;
                if (relu) {
                    v0 = fmaxf(v0, 0.f); v1 = fmaxf(v1, 0.f);
                    v2 = fmaxf(v2, 0.f); v3 = fmaxf(v3, 0.f);
                }
                if (outf) {
                    float4 o; o.x = v0; o.y = v1; o.z = v2; o.w = v3;
                    *(float4*)(outf + (size_t)rr * N + c) = o;
                } else if (out8) {
                    int enc = __builtin_amdgcn_cvt_pk_fp8_f32(v0, v1, 0, false);
                    enc = __builtin_amdgcn_cvt_pk_fp8_f32(v2, v3, enc, true);
                    *(uint32_t*)(out8 + (size_t)rr * N + c) = (uint32_t)enc;
                } else {
                    uint2 o;
                    o.x = (uint32_t)f2bf(v0) | ((uint32_t)f2bf(v1) << 16);
                    o.y = (uint32_t)f2bf(v2) | ((uint32_t)f2bf(v3) << 16);
                    *(uint2*)(outb + (size_t)rr * N + c) = o;
                }
            }
        }
    }
}

extern "C" void kernel_launch(void* const* d_in, const int* in_sizes, int n_in,
                              void* d_out, int out_size, void* d_ws, size_t ws_size,
                              hipStream_t stream) {
    const float* x    = (const float*)d_in[0];
    const int*   ei   = (const int*)d_in[1];
    const float* W1a  = (const float*)d_in[2];
    const float* b1a  = (const float*)d_in[3];
    const float* W1b  = (const float*)d_in[4];
    const float* b1b  = (const float*)d_in[5];
    const float* W2a  = (const float*)d_in[6];
    const float* b2a  = (const float*)d_in[7];
    const float* W2b  = (const float*)d_in[8];
    const float* b2b  = (const float*)d_in[9];
    const float* eps1 = (const float*)d_in[10];
    const float* eps2 = (const float*)d_in[11];
    const int nE = in_sizes[1] / 2;
    const int* srcv = ei;
    const int* dstv = ei + nE;

    // ---- compact workspace layout (~215 MB) ----
    char* ws = (char*)d_ws;
    int*    off    = (int*)(ws);                        // 100001 ints
    int*    cursor = (int*)(ws + 524288);               // 100000 ints
    int*    csr    = (int*)(ws + 1048576);              // 1.6M ints
    ushort* Wt1a   = (ushort*)(ws + 8388608);           // [512][256] bf16
    ushort* Wt1b   = Wt1a + 512 * 256;                  // [512][512]
    ushort* Wt2a   = Wt1b + 512 * 512;                  // [512][512]
    ushort* Wt2b   = Wt2a + 512 * 512;                  // [256][512]
    char*   P      = ws + 10485760;                     // 102,400,000 B slot
    char*   Q      = ws + 10485760 + 102400000;         // 102,400,000 B slot
    uint8_t* x8    = (uint8_t*)P;  // [100000,256] fp8 (dead before h1 written)
    ushort* agg1b  = (ushort*)Q;   // [100000,256] bf16 (dead before h2f8 written)
    ushort* h1     = (ushort*)P;   // [100000,512] bf16
    uint8_t* h2f8  = (uint8_t*)Q;  // [100000,512] fp8
    ushort* agg2b  = (ushort*)P;   // [100000,512] bf16 (h1 dead)
    ushort* h3     = (ushort*)Q;   // [100000,512] bf16 (h2f8 dead)

    // ---- CSR build (by dst) ----
    zero_i32<<<(NN + 255) / 256, 256, 0, stream>>>(cursor, NN);
    count_deg<<<(nE + 255) / 256, 256, 0, stream>>>(dstv, cursor, nE);
    scan_excl<<<1, 1024, 0, stream>>>(cursor, off, NN);
    zero_i32<<<(NN + 255) / 256, 256, 0, stream>>>(cursor, NN);
    fill_csr<<<(nE + 255) / 256, 256, 0, stream>>>(srcv, dstv, off, cursor, csr, nE);

    // ---- weights -> bf16 transposed (one launch); x -> fp8 ----
    prep_w4<<<(786432 + 255) / 256, 256, 0, stream>>>(W1a, W1b, W2a, W2b,
                                                      Wt1a, Wt1b, Wt2a, Wt2b);
    cast_f32_fp8<<<(NN * NFEATD / 8 + 255) / 256, 256, 0, stream>>>(x, x8, NN * NFEATD);

    // ---- layer 1: agg -> MLP ----
    gather256f8<<<(NN * 64) / 256, 256, 0, stream>>>(x8, off, csr, eps1, agg1b);
    dim3 g1(NHIDD / 128, (NN + 127) / 128);   // x = col block (inner -> A-panel reuse)
    gemm_bt<<<g1, 256, 0, stream>>>(agg1b, Wt1a, b1a, nullptr, nullptr, h1, NN, NHIDD, NFEATD, 1);
    gemm_bt<<<g1, 256, 0, stream>>>(h1, Wt1b, b1b, nullptr, h2f8, nullptr, NN, NHIDD, NHIDD, 1);

    // ---- layer 2: agg -> MLP ----
    gather512f8<<<(NN * 64) / 256, 256, 0, stream>>>(h2f8, off, csr, eps2, agg2b);
    gemm_bt<<<g1, 256, 0, stream>>>(agg2b, Wt2a, b2a, nullptr, nullptr, h3, NN, NHIDD, NHIDD, 1);
    dim3 g2(NCLASSD / 128, (NN + 127) / 128);
    gemm_bt<<<g2, 256, 0, stream>>>(h3, Wt2b, b2b, (float*)d_out, nullptr, nullptr, NN, NCLASSD, NHIDD, 0);
}

// Round 7
// 925.167 us; speedup vs baseline: 1.2462x; 1.2462x over previous
//
#include <hip/hip_runtime.h>
#include <hip/hip_bf16.h>
#include <stdint.h>

#define NN 100000
#define NFEATD 256
#define NHIDD 512
#define NCLASSD 256

typedef short bf16x8 __attribute__((ext_vector_type(8)));
typedef float f32x4 __attribute__((ext_vector_type(4)));
typedef float f32x2 __attribute__((ext_vector_type(2)));

__device__ __forceinline__ float bf2f(uint32_t u) {
    union { uint32_t i; float f; } v; v.i = u << 16; return v.f;
}
__device__ __forceinline__ ushort f2bf(float f) {
    uint32_t x = __float_as_uint(f);
    uint32_t r = (x + 0x7FFF + ((x >> 16) & 1)) >> 16;
    return (ushort)r;
}

// ---------------- small utility kernels ----------------
__global__ void zero_i32(int* __restrict__ p, int n) {
    int i = blockIdx.x * 256 + threadIdx.x;
    if (i < n) p[i] = 0;
}

__global__ void count_deg(const int* __restrict__ dst, int* __restrict__ deg, int nE) {
    int e = blockIdx.x * 256 + threadIdx.x;
    if (e < nE) atomicAdd(&deg[dst[e]], 1);
}

// single-block exclusive scan over n ints, 1024 threads
__global__ __launch_bounds__(1024) void scan_excl(const int* __restrict__ deg,
                                                  int* __restrict__ off, int n) {
    __shared__ int wsum[16];
    __shared__ int carry_s;
    const int tid = threadIdx.x;
    const int lane = tid & 63, wv = tid >> 6;
    if (tid == 0) carry_s = 0;
    __syncthreads();
    for (int base = 0; base < n; base += 1024) {
        int i = base + tid;
        int v = (i < n) ? deg[i] : 0;
        int x = v;
#pragma unroll
        for (int d = 1; d < 64; d <<= 1) {
            int y = __shfl_up(x, d, 64);
            if (lane >= d) x += y;
        }
        if (lane == 63) wsum[wv] = x;
        __syncthreads();
        if (wv == 0 && lane < 16) {
            int s = wsum[lane];
#pragma unroll
            for (int d = 1; d < 16; d <<= 1) {
                int y = __shfl_up(s, d, 16);
                if (lane >= d) s += y;
            }
            wsum[lane] = s;
        }
        __syncthreads();
        int carry = carry_s;
        int wprefix = (wv == 0) ? 0 : wsum[wv - 1];
        if (i < n) off[i] = carry + wprefix + x - v;
        __syncthreads();
        if (tid == 0) carry_s = carry + wsum[15];
        __syncthreads();
    }
    if (tid == 0) off[n] = carry_s;
}

__global__ void fill_csr(const int* __restrict__ src, const int* __restrict__ dst,
                         const int* __restrict__ off, int* __restrict__ cursor,
                         int* __restrict__ csr, int nE) {
    int e = blockIdx.x * 256 + threadIdx.x;
    if (e >= nE) return;
    int d = dst[e];
    int p = off[d] + atomicAdd(&cursor[d], 1);
    csr[p] = src[e];
}

// ---------------- weight prep: all four [K][N] f32 -> [N][K] bf16 in ONE launch ------
__global__ void prep_w4(const float* __restrict__ W1a, const float* __restrict__ W1b,
                        const float* __restrict__ W2a, const float* __restrict__ W2b,
                        ushort* __restrict__ Wt1a, ushort* __restrict__ Wt1b,
                        ushort* __restrict__ Wt2a, ushort* __restrict__ Wt2b) {
    int idx = blockIdx.x * 256 + threadIdx.x;
    // segment sizes: 256*512, 512*512, 512*512, 512*256
    if (idx < 131072) {                       // W1a: K=256, N=512
        int k = idx >> 9, n = idx & 511;
        Wt1a[n * 256 + k] = f2bf(W1a[idx]);
    } else if (idx < 131072 + 262144) {       // W1b: K=512, N=512
        int i = idx - 131072;
        int k = i >> 9, n = i & 511;
        Wt1b[n * 512 + k] = f2bf(W1b[i]);
    } else if (idx < 131072 + 524288) {       // W2a: K=512, N=512
        int i = idx - (131072 + 262144);
        int k = i >> 9, n = i & 511;
        Wt2a[n * 512 + k] = f2bf(W2a[i]);
    } else if (idx < 131072 + 524288 + 131072) {  // W2b: K=512, N=256
        int i = idx - (131072 + 524288);
        int k = i >> 8, n = i & 255;
        Wt2b[n * 512 + k] = f2bf(W2b[i]);
    }
}

// f32 -> fp8 e4m3 cast, 8 elems/thread
__global__ void cast_f32_fp8(const float* __restrict__ a, uint8_t* __restrict__ o, int n) {
    int i = (blockIdx.x * 256 + threadIdx.x) * 8;
    if (i >= n) return;
    float4 v0 = *(const float4*)(a + i);
    float4 v1 = *(const float4*)(a + i + 4);
    int lo = __builtin_amdgcn_cvt_pk_fp8_f32(v0.x, v0.y, 0, false);
    lo = __builtin_amdgcn_cvt_pk_fp8_f32(v0.z, v0.w, lo, true);
    int hi = __builtin_amdgcn_cvt_pk_fp8_f32(v1.x, v1.y, 0, false);
    hi = __builtin_amdgcn_cvt_pk_fp8_f32(v1.z, v1.w, hi, true);
    uint2 r; r.x = (uint32_t)lo; r.y = (uint32_t)hi;
    *(uint2*)(o + i) = r;
}

// decode 4 fp8 (one uint32) -> packed-f32 accumulate (v_pk_add_f32)
__device__ __forceinline__ void accp(uint32_t p, f32x2& lo, f32x2& hi) {
    lo += __builtin_amdgcn_cvt_pk_f32_fp8((int)p, false);
    hi += __builtin_amdgcn_cvt_pk_f32_fp8((int)p, true);
}

// ---------------- CSR gather: agg[n] = (1+eps)*x[n] + sum_{s in nbr(n)} x[s] ---------
// At its structural floor: compulsory L2-fill = table(51.2MB) x 8 XCDs ~= 402 MB (measured).
// one wave per node, F=256 fp8 input (uint/lane = 4 fp8), unroll 8, packed-f32 acc
__global__ void gather256f8(const uint8_t* __restrict__ X8, const int* __restrict__ off,
                            const int* __restrict__ csr, const float* __restrict__ eps,
                            ushort* __restrict__ out) {
    int node = (blockIdx.x * 256 + threadIdx.x) >> 6;
    if (node >= NN) return;
    int lane = threadIdx.x & 63;
    float sc = 1.0f + *eps;
    f32x2 scv = {sc, sc};
    const uint32_t* X1 = (const uint32_t*)X8;  // 64 uints per row
    f32x2 lo = {0.f, 0.f}, hi = {0.f, 0.f};
    {
        uint32_t p = X1[(size_t)node * 64 + lane];
        lo = scv * __builtin_amdgcn_cvt_pk_f32_fp8((int)p, false);
        hi = scv * __builtin_amdgcn_cvt_pk_f32_fp8((int)p, true);
    }
    int e = off[node], e1 = off[node + 1];
    for (; e + 7 < e1; e += 8) {
        uint32_t p[8];
#pragma unroll
        for (int t = 0; t < 8; ++t) p[t] = X1[(size_t)csr[e + t] * 64 + lane];
#pragma unroll
        for (int t = 0; t < 8; ++t) accp(p[t], lo, hi);
    }
    for (; e < e1; ++e)
        accp(X1[(size_t)csr[e] * 64 + lane], lo, hi);
    uint2 r;
    r.x = (uint32_t)f2bf(lo[0]) | ((uint32_t)f2bf(lo[1]) << 16);
    r.y = (uint32_t)f2bf(hi[0]) | ((uint32_t)f2bf(hi[1]) << 16);
    *(uint2*)(out + (size_t)node * 256 + lane * 4) = r;
}

// one wave per node, F=512 fp8 input (uint2/lane = 8 fp8), unroll 8, packed-f32 acc
__global__ void gather512f8(const uint8_t* __restrict__ H8, const int* __restrict__ off,
                            const int* __restrict__ csr, const float* __restrict__ eps,
                            ushort* __restrict__ out) {
    int node = (blockIdx.x * 256 + threadIdx.x) >> 6;
    if (node >= NN) return;
    int lane = threadIdx.x & 63;
    float sc = 1.0f + *eps;
    f32x2 scv = {sc, sc};
    const uint2* H2 = (const uint2*)H8;  // 64 uint2 per row
    f32x2 l0 = {0.f, 0.f}, h0 = {0.f, 0.f}, l1 = {0.f, 0.f}, h1 = {0.f, 0.f};
    {
        uint2 p = H2[(size_t)node * 64 + lane];
        l0 = scv * __builtin_amdgcn_cvt_pk_f32_fp8((int)p.x, false);
        h0 = scv * __builtin_amdgcn_cvt_pk_f32_fp8((int)p.x, true);
        l1 = scv * __builtin_amdgcn_cvt_pk_f32_fp8((int)p.y, false);
        h1 = scv * __builtin_amdgcn_cvt_pk_f32_fp8((int)p.y, true);
    }
    int e = off[node], e1 = off[node + 1];
    for (; e + 7 < e1; e += 8) {
        uint2 p[8];
#pragma unroll
        for (int t = 0; t < 8; ++t) p[t] = H2[(size_t)csr[e + t] * 64 + lane];
#pragma unroll
        for (int t = 0; t < 8; ++t) {
            accp(p[t].x, l0, h0);
            accp(p[t].y, l1, h1);
        }
    }
    for (; e < e1; ++e) {
        uint2 p = H2[(size_t)csr[e] * 64 + lane];
        accp(p.x, l0, h0);
        accp(p.y, l1, h1);
    }
    uint4 r;
    r.x = (uint32_t)f2bf(l0[0]) | ((uint32_t)f2bf(l0[1]) << 16);
    r.y = (uint32_t)f2bf(h0[0]) | ((uint32_t)f2bf(h0[1]) << 16);
    r.z = (uint32_t)f2bf(l1[0]) | ((uint32_t)f2bf(l1[1]) << 16);
    r.w = (uint32_t)f2bf(h1[0]) | ((uint32_t)f2bf(h1[1]) << 16);
    *(uint4*)(out + (size_t)node * 512 + lane * 8) = r;
}

// ---------------- GEMM v3b: 128x256 tile, 8 waves, 2-slot dbuf LDS, 1 sync/chunk -----
// (proven round-5 structure; round-6's B-in-reg variant spilled and was reverted)
// C[M,N] = A[M,K](bf16) * Bt[N,K](bf16)^T + bias, opt relu
// T3-minimum schedule: per 32-K chunk,
//   {issue next-chunk global_load_lds -> ds_read(cur) -> MFMA -> __syncthreads()}
// NEW: 1D grid + XCD-bijective swizzle (m204): each XCD gets a contiguous chunk of
// (row-panel x col) space, so both col-blocks of an A row-panel land in the SAME XCD's
// L2 (A-panel fabric traffic /2). Perf-only mapping; correctness independent.

__device__ __forceinline__ void stage_a(const ushort* __restrict__ A, int K, int row0,
                                        int kc, ushort* dst, int tid, int Mm1) {
    int r = tid >> 2, c = tid & 3;                 // 128 rows x 4 col-blocks
    int gr = row0 + r; if (gr > Mm1) gr = Mm1;
    const ushort* gp = A + (size_t)gr * K + kc + c * 8;
    __builtin_amdgcn_global_load_lds((const __attribute__((address_space(1))) void*)gp,
        (__attribute__((address_space(3))) void*)(dst + tid * 8), 16, 0, 0);
}

__device__ __forceinline__ void stage_b(const ushort* __restrict__ Bt, int K, int col0,
                                        int kc, ushort* dst, int tid) {
#pragma unroll
    for (int i = 0; i < 2; ++i) {
        int u = i * 512 + tid;                     // 256 rows x 4 col-blocks
        int r = u >> 2, c = u & 3;
        const ushort* gp = Bt + (size_t)(col0 + r) * K + kc + c * 8;
        __builtin_amdgcn_global_load_lds((const __attribute__((address_space(1))) void*)gp,
            (__attribute__((address_space(3))) void*)(dst + u * 8), 16, 0, 0);
    }
}

__global__ __launch_bounds__(512, 4) void gemm_bt(
    const ushort* __restrict__ A, const ushort* __restrict__ Bt,
    const float* __restrict__ bias, float* __restrict__ outf,
    uint8_t* __restrict__ out8, ushort* __restrict__ outb,
    int M, int N, int K, int relu)
{
    __shared__ ushort smem[2][12288];   // slot: As[128*32] + Bs[256*32] = 24 KB
    const int tid = threadIdx.x;
    const int wave = tid >> 6, lane = tid & 63;
    const int quad = lane >> 4, lrow = lane & 15;
    const int wr = wave >> 2, wcn = wave & 3;      // 2M x 4N waves, 64x64 out each
    // XCD-bijective swizzle (m204): contiguous chunk of work per XCD
    const int nwg = gridDim.x;
    const int q = nwg >> 3, r8 = nwg & 7;
    const int xcd = blockIdx.x & 7, seq = blockIdx.x >> 3;
    const int k = ((xcd < r8) ? xcd * (q + 1) : r8 * (q + 1) + (xcd - r8) * q) + seq;
    const int ncol = N >> 8;                        // col blocks of 256
    const int row0 = (k / ncol) * 128, col0 = (k % ncol) * 256;
    const int NC = K >> 5;

    f32x4 acc[4][4] = {};

    // prologue: stage chunk 0, full drain
    stage_a(A, K, row0, 0, smem[0], tid, M - 1);
    stage_b(Bt, K, col0, 0, smem[0] + 4096, tid);
    __syncthreads();

    for (int t = 0; t < NC; ++t) {
        const ushort* As = smem[t & 1];
        const ushort* Bs = As + 4096;
        if (t + 1 < NC) {   // issue next chunk; flies under ds_read+MFMA below
            stage_a(A, K, row0, (t + 1) << 5, smem[(t + 1) & 1], tid, M - 1);
            stage_b(Bt, K, col0, (t + 1) << 5, smem[(t + 1) & 1] + 4096, tid);
        }
        bf16x8 af[4], bfr[4];
#pragma unroll
        for (int m = 0; m < 4; ++m)
            af[m] = *(const bf16x8*)(As + (wr * 64 + m * 16 + lrow) * 32 + quad * 8);
#pragma unroll
        for (int n = 0; n < 4; ++n)
            bfr[n] = *(const bf16x8*)(Bs + (wcn * 64 + n * 16 + lrow) * 32 + quad * 8);
        __builtin_amdgcn_s_setprio(1);
#pragma unroll
        for (int m = 0; m < 4; ++m)
#pragma unroll
            for (int n = 0; n < 4; ++n)
                acc[m][n] = __builtin_amdgcn_mfma_f32_16x16x32_bf16(bfr[n], af[m], acc[m][n], 0, 0, 0);
        __builtin_amdgcn_s_setprio(0);
        __syncthreads();    // drains next-chunk loads + fences WAR for slot reuse
    }

    // epilogue: swapped-operand C/D layout: M-row = lane&15, N-col = quad*4 + reg
#pragma unroll
    for (int m = 0; m < 4; ++m) {
        int rr = row0 + wr * 64 + m * 16 + lrow;
        if (rr < M) {
#pragma unroll
            for (int n = 0; n < 4; ++n) {
                int c = col0 + wcn * 64 + n * 16 + quad * 4;
                float4 bv = *(const float4*)(bias + c);
                float v0 = acc[m][n][0] + bv.x;
                float v1 = acc[m][n][1] + bv.y;
                float v2 = acc[m][n][2] + bv.z;
                float v3 = acc[m][n][3] + bv.w;
                if (relu) {
                    v0 = fmaxf(v0, 0.f); v1 = fmaxf(v1, 0.f);
                    v2 = fmaxf(v2, 0.f); v3 = fmaxf(v3, 0.f);
                }
                if (outf) {
                    float4 o; o.x = v0; o.y = v1; o.z = v2; o.w = v3;
                    *(float4*)(outf + (size_t)rr * N + c) = o;
                } else if (out8) {
                    int enc = __builtin_amdgcn_cvt_pk_fp8_f32(v0, v1, 0, false);
                    enc = __builtin_amdgcn_cvt_pk_fp8_f32(v2, v3, enc, true);
                    *(uint32_t*)(out8 + (size_t)rr * N + c) = (uint32_t)enc;
                } else {
                    uint2 o;
                    o.x = (uint32_t)f2bf(v0) | ((uint32_t)f2bf(v1) << 16);
                    o.y = (uint32_t)f2bf(v2) | ((uint32_t)f2bf(v3) << 16);
                    *(uint2*)(outb + (size_t)rr * N + c) = o;
                }
            }
        }
    }
}

extern "C" void kernel_launch(void* const* d_in, const int* in_sizes, int n_in,
                              void* d_out, int out_size, void* d_ws, size_t ws_size,
                              hipStream_t stream) {
    const float* x    = (const float*)d_in[0];
    const int*   ei   = (const int*)d_in[1];
    const float* W1a  = (const float*)d_in[2];
    const float* b1a  = (const float*)d_in[3];
    const float* W1b  = (const float*)d_in[4];
    const float* b1b  = (const float*)d_in[5];
    const float* W2a  = (const float*)d_in[6];
    const float* b2a  = (const float*)d_in[7];
    const float* W2b  = (const float*)d_in[8];
    const float* b2b  = (const float*)d_in[9];
    const float* eps1 = (const float*)d_in[10];
    const float* eps2 = (const float*)d_in[11];
    const int nE = in_sizes[1] / 2;
    const int* srcv = ei;
    const int* dstv = ei + nE;

    // ---- compact workspace layout (~215 MB) ----
    char* ws = (char*)d_ws;
    int*    off    = (int*)(ws);                        // 100001 ints
    int*    cursor = (int*)(ws + 524288);               // 100000 ints
    int*    csr    = (int*)(ws + 1048576);              // 1.6M ints
    ushort* Wt1a   = (ushort*)(ws + 8388608);           // [512][256] bf16
    ushort* Wt1b   = Wt1a + 512 * 256;                  // [512][512]
    ushort* Wt2a   = Wt1b + 512 * 512;                  // [512][512]
    ushort* Wt2b   = Wt2a + 512 * 512;                  // [256][512]
    char*   P      = ws + 10485760;                     // 102,400,000 B slot
    char*   Q      = ws + 10485760 + 102400000;         // 102,400,000 B slot
    uint8_t* x8    = (uint8_t*)P;  // [100000,256] fp8 (dead before h1 written)
    ushort* agg1b  = (ushort*)Q;   // [100000,256] bf16 (dead before h2f8 written)
    ushort* h1     = (ushort*)P;   // [100000,512] bf16
    uint8_t* h2f8  = (uint8_t*)Q;  // [100000,512] fp8
    ushort* agg2b  = (ushort*)P;   // [100000,512] bf16 (h1 dead)
    ushort* h3     = (ushort*)Q;   // [100000,512] bf16 (h2f8 dead)

    // ---- CSR build (by dst) ----
    zero_i32<<<(NN + 255) / 256, 256, 0, stream>>>(cursor, NN);
    count_deg<<<(nE + 255) / 256, 256, 0, stream>>>(dstv, cursor, nE);
    scan_excl<<<1, 1024, 0, stream>>>(cursor, off, NN);
    zero_i32<<<(NN + 255) / 256, 256, 0, stream>>>(cursor, NN);
    fill_csr<<<(nE + 255) / 256, 256, 0, stream>>>(srcv, dstv, off, cursor, csr, nE);

    // ---- weights -> bf16 transposed (one launch); x -> fp8 ----
    prep_w4<<<(786432 + 255) / 256, 256, 0, stream>>>(W1a, W1b, W2a, W2b,
                                                      Wt1a, Wt1b, Wt2a, Wt2b);
    cast_f32_fp8<<<(NN * NFEATD / 8 + 255) / 256, 256, 0, stream>>>(x, x8, NN * NFEATD);

    // ---- layer 1: agg -> MLP ----
    gather256f8<<<(NN * 64) / 256, 256, 0, stream>>>(x8, off, csr, eps1, agg1b);
    const int nrow = (NN + 127) / 128;               // 782 row panels
    gemm_bt<<<nrow * (NHIDD / 256), 512, 0, stream>>>(agg1b, Wt1a, b1a, nullptr, nullptr, h1, NN, NHIDD, NFEATD, 1);
    gemm_bt<<<nrow * (NHIDD / 256), 512, 0, stream>>>(h1, Wt1b, b1b, nullptr, h2f8, nullptr, NN, NHIDD, NHIDD, 1);

    // ---- layer 2: agg -> MLP ----
    gather512f8<<<(NN * 64) / 256, 256, 0, stream>>>(h2f8, off, csr, eps2, agg2b);
    gemm_bt<<<nrow * (NHIDD / 256), 512, 0, stream>>>(agg2b, Wt2a, b2a, nullptr, nullptr, h3, NN, NHIDD, NHIDD, 1);
    gemm_bt<<<nrow * (NCLASSD / 256), 512, 0, stream>>>(h3, Wt2b, b2b, (float*)d_out, nullptr, nullptr, NN, NCLASSD, NHIDD, 0);
}

// Round 8
// 837.781 us; speedup vs baseline: 1.3761x; 1.1043x over previous
//
#include <hip/hip_runtime.h>
#include <hip/hip_bf16.h>
#include <stdint.h>

#define NN 100000
#define NFEATD 256
#define NHIDD 512
#define NCLASSD 256

typedef short bf16x8 __attribute__((ext_vector_type(8)));
typedef float f32x4 __attribute__((ext_vector_type(4)));
typedef float f32x2 __attribute__((ext_vector_type(2)));

__device__ __forceinline__ float bf2f(uint32_t u) {
    union { uint32_t i; float f; } v; v.i = u << 16; return v.f;
}
__device__ __forceinline__ ushort f2bf(float f) {
    uint32_t x = __float_as_uint(f);
    uint32_t r = (x + 0x7FFF + ((x >> 16) & 1)) >> 16;
    return (ushort)r;
}

// ---------------- small utility kernels ----------------
__global__ void zero_i32(int* __restrict__ p, int n) {
    int i = blockIdx.x * 256 + threadIdx.x;
    if (i < n) p[i] = 0;
}

// fused independent prep work: count_deg | prep_w4 | cast_f32_fp8 (blockIdx ranges)
__global__ void fused_misc(const int* __restrict__ dst, int* __restrict__ deg, int nE, int cb,
                           const float* __restrict__ W1a, const float* __restrict__ W1b,
                           const float* __restrict__ W2a, const float* __restrict__ W2b,
                           ushort* __restrict__ Wt1a, ushort* __restrict__ Wt1b,
                           ushort* __restrict__ Wt2a, ushort* __restrict__ Wt2b,
                           const float* __restrict__ x, uint8_t* __restrict__ x8, int nx) {
    int b = blockIdx.x;
    if (b < cb) {                                  // ---- count_deg ----
        int e = b * 256 + threadIdx.x;
        if (e < nE) atomicAdd(&deg[dst[e]], 1);
    } else if (b < cb + 3072) {                    // ---- prep_w4 (786432 = 3072*256) ----
        int idx = (b - cb) * 256 + threadIdx.x;
        if (idx < 131072) {                        // W1a: K=256, N=512
            int k = idx >> 9, n = idx & 511;
            Wt1a[n * 256 + k] = f2bf(W1a[idx]);
        } else if (idx < 131072 + 262144) {        // W1b: K=512, N=512
            int i = idx - 131072;
            int k = i >> 9, n = i & 511;
            Wt1b[n * 512 + k] = f2bf(W1b[i]);
        } else if (idx < 131072 + 524288) {        // W2a: K=512, N=512
            int i = idx - (131072 + 262144);
            int k = i >> 9, n = i & 511;
            Wt2a[n * 512 + k] = f2bf(W2a[i]);
        } else {                                   // W2b: K=512, N=256
            int i = idx - (131072 + 524288);
            int k = i >> 8, n = i & 255;
            Wt2b[n * 512 + k] = f2bf(W2b[i]);
        }
    } else {                                       // ---- cast_f32_fp8 ----
        int i = ((b - cb - 3072) * 256 + threadIdx.x) * 8;
        if (i < nx) {
            float4 v0 = *(const float4*)(x + i);
            float4 v1 = *(const float4*)(x + i + 4);
            int lo = __builtin_amdgcn_cvt_pk_fp8_f32(v0.x, v0.y, 0, false);
            lo = __builtin_amdgcn_cvt_pk_fp8_f32(v0.z, v0.w, lo, true);
            int hi = __builtin_amdgcn_cvt_pk_fp8_f32(v1.x, v1.y, 0, false);
            hi = __builtin_amdgcn_cvt_pk_fp8_f32(v1.z, v1.w, hi, true);
            uint2 r; r.x = (uint32_t)lo; r.y = (uint32_t)hi;
            *(uint2*)(x8 + i) = r;
        }
    }
}

// ---------------- parallel exclusive scan (replaces single-block scan_excl) ----------
// 512 elems/block partial sums
__global__ void scan_part(const int* __restrict__ deg, int* __restrict__ part, int n) {
    int base = blockIdx.x * 512;
    int tid = threadIdx.x;
    int i0 = base + tid * 2;
    int v0 = (i0 < n) ? deg[i0] : 0;
    int v1 = (i0 + 1 < n) ? deg[i0 + 1] : 0;
    int s = v0 + v1;
#pragma unroll
    for (int d = 1; d < 64; d <<= 1) s += __shfl_xor(s, d, 64);
    __shared__ int ws[4];
    if ((tid & 63) == 0) ws[tid >> 6] = s;
    __syncthreads();
    if (tid == 0) part[blockIdx.x] = ws[0] + ws[1] + ws[2] + ws[3];
}

// exclusive-scan np (<=256) partials in one block; write grand total to *total
__global__ void scan_mid(int* __restrict__ part, int* __restrict__ total, int np) {
    int tid = threadIdx.x;
    int lane = tid & 63, wv = tid >> 6;
    int v = (tid < np) ? part[tid] : 0;
    int x = v;
#pragma unroll
    for (int d = 1; d < 64; d <<= 1) { int y = __shfl_up(x, d, 64); if (lane >= d) x += y; }
    __shared__ int ws[4];
    if (lane == 63) ws[wv] = x;
    __syncthreads();
    int wp = 0;
#pragma unroll
    for (int j = 0; j < 4; ++j) if (j < wv) wp += ws[j];
    if (tid < np) part[tid] = wp + x - v;
    if (tid == 255) total[0] = wp + x;
}

// local exclusive scan within 512-chunk + block prefix -> off
__global__ void scan_apply(const int* __restrict__ deg, const int* __restrict__ part,
                           int* __restrict__ off, int n) {
    int base = blockIdx.x * 512;
    int tid = threadIdx.x;
    int lane = tid & 63, wv = tid >> 6;
    int i0 = base + tid * 2;
    int v0 = (i0 < n) ? deg[i0] : 0;
    int v1 = (i0 + 1 < n) ? deg[i0 + 1] : 0;
    int s = v0 + v1;
    int x = s;
#pragma unroll
    for (int d = 1; d < 64; d <<= 1) { int y = __shfl_up(x, d, 64); if (lane >= d) x += y; }
    __shared__ int ws[4];
    if (lane == 63) ws[wv] = x;
    __syncthreads();
    int wp = 0;
#pragma unroll
    for (int j = 0; j < 4; ++j) if (j < wv) wp += ws[j];
    int excl = part[blockIdx.x] + wp + x - s;
    if (i0 < n) off[i0] = excl;
    if (i0 + 1 < n) off[i0 + 1] = excl + v0;
}

// fill via atomicSub on deg (destroys deg; no second zero pass needed).
// within-node neighbor order is irrelevant (sum aggregation).
__global__ void fill_csr2(const int* __restrict__ src, const int* __restrict__ dst,
                          const int* __restrict__ off, int* __restrict__ deg,
                          int* __restrict__ csr, int nE) {
    int e = blockIdx.x * 256 + threadIdx.x;
    if (e >= nE) return;
    int d = dst[e];
    int r = atomicSub(&deg[d], 1);
    csr[off[d] + r - 1] = src[e];
}

// decode 4 fp8 (one uint32) -> packed-f32 accumulate (v_pk_add_f32)
__device__ __forceinline__ void accp(uint32_t p, f32x2& lo, f32x2& hi) {
    lo += __builtin_amdgcn_cvt_pk_f32_fp8((int)p, false);
    hi += __builtin_amdgcn_cvt_pk_f32_fp8((int)p, true);
}

// ---------------- CSR gather: agg[n] = (1+eps)*x[n] + sum_{s in nbr(n)} x[s] ---------
// At its structural floor: compulsory L2-fill = table(51.2MB) x 8 XCDs ~= 402 MB (measured).
// one wave per node, F=256 fp8 input (uint/lane = 4 fp8), unroll 8, packed-f32 acc
__global__ void gather256f8(const uint8_t* __restrict__ X8, const int* __restrict__ off,
                            const int* __restrict__ csr, const float* __restrict__ eps,
                            ushort* __restrict__ out) {
    int node = (blockIdx.x * 256 + threadIdx.x) >> 6;
    if (node >= NN) return;
    int lane = threadIdx.x & 63;
    float sc = 1.0f + *eps;
    f32x2 scv = {sc, sc};
    const uint32_t* X1 = (const uint32_t*)X8;  // 64 uints per row
    f32x2 lo = {0.f, 0.f}, hi = {0.f, 0.f};
    {
        uint32_t p = X1[(size_t)node * 64 + lane];
        lo = scv * __builtin_amdgcn_cvt_pk_f32_fp8((int)p, false);
        hi = scv * __builtin_amdgcn_cvt_pk_f32_fp8((int)p, true);
    }
    int e = off[node], e1 = off[node + 1];
    for (; e + 7 < e1; e += 8) {
        uint32_t p[8];
#pragma unroll
        for (int t = 0; t < 8; ++t) p[t] = X1[(size_t)csr[e + t] * 64 + lane];
#pragma unroll
        for (int t = 0; t < 8; ++t) accp(p[t], lo, hi);
    }
    for (; e < e1; ++e)
        accp(X1[(size_t)csr[e] * 64 + lane], lo, hi);
    uint2 r;
    r.x = (uint32_t)f2bf(lo[0]) | ((uint32_t)f2bf(lo[1]) << 16);
    r.y = (uint32_t)f2bf(hi[0]) | ((uint32_t)f2bf(hi[1]) << 16);
    *(uint2*)(out + (size_t)node * 256 + lane * 4) = r;
}

// one wave per node, F=512 fp8 input (uint2/lane = 8 fp8), unroll 8, packed-f32 acc
__global__ void gather512f8(const uint8_t* __restrict__ H8, const int* __restrict__ off,
                            const int* __restrict__ csr, const float* __restrict__ eps,
                            ushort* __restrict__ out) {
    int node = (blockIdx.x * 256 + threadIdx.x) >> 6;
    if (node >= NN) return;
    int lane = threadIdx.x & 63;
    float sc = 1.0f + *eps;
    f32x2 scv = {sc, sc};
    const uint2* H2 = (const uint2*)H8;  // 64 uint2 per row
    f32x2 l0 = {0.f, 0.f}, h0 = {0.f, 0.f}, l1 = {0.f, 0.f}, h1 = {0.f, 0.f};
    {
        uint2 p = H2[(size_t)node * 64 + lane];
        l0 = scv * __builtin_amdgcn_cvt_pk_f32_fp8((int)p.x, false);
        h0 = scv * __builtin_amdgcn_cvt_pk_f32_fp8((int)p.x, true);
        l1 = scv * __builtin_amdgcn_cvt_pk_f32_fp8((int)p.y, false);
        h1 = scv * __builtin_amdgcn_cvt_pk_f32_fp8((int)p.y, true);
    }
    int e = off[node], e1 = off[node + 1];
    for (; e + 7 < e1; e += 8) {
        uint2 p[8];
#pragma unroll
        for (int t = 0; t < 8; ++t) p[t] = H2[(size_t)csr[e + t] * 64 + lane];
#pragma unroll
        for (int t = 0; t < 8; ++t) {
            accp(p[t].x, l0, h0);
            accp(p[t].y, l1, h1);
        }
    }
    for (; e < e1; ++e) {
        uint2 p = H2[(size_t)csr[e] * 64 + lane];
        accp(p.x, l0, h0);
        accp(p.y, l1, h1);
    }
    uint4 r;
    r.x = (uint32_t)f2bf(l0[0]) | ((uint32_t)f2bf(l0[1]) << 16);
    r.y = (uint32_t)f2bf(h0[0]) | ((uint32_t)f2bf(h0[1]) << 16);
    r.z = (uint32_t)f2bf(l1[0]) | ((uint32_t)f2bf(l1[1]) << 16);
    r.w = (uint32_t)f2bf(h1[0]) | ((uint32_t)f2bf(h1[1]) << 16);
    *(uint4*)(out + (size_t)node * 512 + lane * 8) = r;
}

// ---------------- GEMM v3b: 128x256 tile, 8 waves, 2-slot dbuf LDS, 1 sync/chunk -----
// Proven structure (r5/r7). T3-minimum schedule: per 32-K chunk,
//   {issue next-chunk global_load_lds -> ds_read(cur) -> MFMA -> __syncthreads()}
// 1D grid + XCD-bijective swizzle (m204). Operand-swapped MFMA -> vectorized stores.

__device__ __forceinline__ void stage_a(const ushort* __restrict__ A, int K, int row0,
                                        int kc, ushort* dst, int tid, int Mm1) {
    int r = tid >> 2, c = tid & 3;                 // 128 rows x 4 col-blocks
    int gr = row0 + r; if (gr > Mm1) gr = Mm1;
    const ushort* gp = A + (size_t)gr * K + kc + c * 8;
    __builtin_amdgcn_global_load_lds((const __attribute__((address_space(1))) void*)gp,
        (__attribute__((address_space(3))) void*)(dst + tid * 8), 16, 0, 0);
}

__device__ __forceinline__ void stage_b(const ushort* __restrict__ Bt, int K, int col0,
                                        int kc, ushort* dst, int tid) {
#pragma unroll
    for (int i = 0; i < 2; ++i) {
        int u = i * 512 + tid;                     // 256 rows x 4 col-blocks
        int r = u >> 2, c = u & 3;
        const ushort* gp = Bt + (size_t)(col0 + r) * K + kc + c * 8;
        __builtin_amdgcn_global_load_lds((const __attribute__((address_space(1))) void*)gp,
            (__attribute__((address_space(3))) void*)(dst + u * 8), 16, 0, 0);
    }
}

__global__ __launch_bounds__(512, 4) void gemm_bt(
    const ushort* __restrict__ A, const ushort* __restrict__ Bt,
    const float* __restrict__ bias, float* __restrict__ outf,
    uint8_t* __restrict__ out8, ushort* __restrict__ outb,
    int M, int N, int K, int relu)
{
    __shared__ ushort smem[2][12288];   // slot: As[128*32] + Bs[256*32] = 24 KB
    const int tid = threadIdx.x;
    const int wave = tid >> 6, lane = tid & 63;
    const int quad = lane >> 4, lrow = lane & 15;
    const int wr = wave >> 2, wcn = wave & 3;      // 2M x 4N waves, 64x64 out each
    // XCD-bijective swizzle (m204)
    const int nwg = gridDim.x;
    const int q = nwg >> 3, r8 = nwg & 7;
    const int xcd = blockIdx.x & 7, seq = blockIdx.x >> 3;
    const int k = ((xcd < r8) ? xcd * (q + 1) : r8 * (q + 1) + (xcd - r8) * q) + seq;
    const int ncol = N >> 8;                        // col blocks of 256
    const int row0 = (k / ncol) * 128, col0 = (k % ncol) * 256;
    const int NC = K >> 5;

    f32x4 acc[4][4] = {};

    // prologue: stage chunk 0, full drain
    stage_a(A, K, row0, 0, smem[0], tid, M - 1);
    stage_b(Bt, K, col0, 0, smem[0] + 4096, tid);
    __syncthreads();

    for (int t = 0; t < NC; ++t) {
        const ushort* As = smem[t & 1];
        const ushort* Bs = As + 4096;
        if (t + 1 < NC) {   // issue next chunk; flies under ds_read+MFMA below
            stage_a(A, K, row0, (t + 1) << 5, smem[(t + 1) & 1], tid, M - 1);
            stage_b(Bt, K, col0, (t + 1) << 5, smem[(t + 1) & 1] + 4096, tid);
        }
        bf16x8 af[4], bfr[4];
#pragma unroll
        for (int m = 0; m < 4; ++m)
            af[m] = *(const bf16x8*)(As + (wr * 64 + m * 16 + lrow) * 32 + quad * 8);
#pragma unroll
        for (int n = 0; n < 4; ++n)
            bfr[n] = *(const bf16x8*)(Bs + (wcn * 64 + n * 16 + lrow) * 32 + quad * 8);
        __builtin_amdgcn_s_setprio(1);
#pragma unroll
        for (int m = 0; m < 4; ++m)
#pragma unroll
            for (int n = 0; n < 4; ++n)
                acc[m][n] = __builtin_amdgcn_mfma_f32_16x16x32_bf16(bfr[n], af[m], acc[m][n], 0, 0, 0);
        __builtin_amdgcn_s_setprio(0);
        __syncthreads();    // drains next-chunk loads + fences WAR for slot reuse
    }

    // epilogue: swapped-operand C/D layout: M-row = lane&15, N-col = quad*4 + reg
#pragma unroll
    for (int m = 0; m < 4; ++m) {
        int rr = row0 + wr * 64 + m * 16 + lrow;
        if (rr < M) {
#pragma unroll
            for (int n = 0; n < 4; ++n) {
                int c = col0 + wcn * 64 + n * 16 + quad * 4;
                float4 bv = *(const float4*)(bias + c);
                float v0 = acc[m][n][0] + bv.x;
                float v1 = acc[m][n][1] + bv.y;
                float v2 = acc[m][n][2] + bv.z;
                float v3 = acc[m][n][3] + bv.w;
                if (relu) {
                    v0 = fmaxf(v0, 0.f); v1 = fmaxf(v1, 0.f);
                    v2 = fmaxf(v2, 0.f); v3 = fmaxf(v3, 0.f);
                }
                if (outf) {
                    float4 o; o.x = v0; o.y = v1; o.z = v2; o.w = v3;
                    *(float4*)(outf + (size_t)rr * N + c) = o;
                } else if (out8) {
                    int enc = __builtin_amdgcn_cvt_pk_fp8_f32(v0, v1, 0, false);
                    enc = __builtin_amdgcn_cvt_pk_fp8_f32(v2, v3, enc, true);
                    *(uint32_t*)(out8 + (size_t)rr * N + c) = (uint32_t)enc;
                } else {
                    uint2 o;
                    o.x = (uint32_t)f2bf(v0) | ((uint32_t)f2bf(v1) << 16);
                    o.y = (uint32_t)f2bf(v2) | ((uint32_t)f2bf(v3) << 16);
                    *(uint2*)(outb + (size_t)rr * N + c) = o;
                }
            }
        }
    }
}

extern "C" void kernel_launch(void* const* d_in, const int* in_sizes, int n_in,
                              void* d_out, int out_size, void* d_ws, size_t ws_size,
                              hipStream_t stream) {
    const float* x    = (const float*)d_in[0];
    const int*   ei   = (const int*)d_in[1];
    const float* W1a  = (const float*)d_in[2];
    const float* b1a  = (const float*)d_in[3];
    const float* W1b  = (const float*)d_in[4];
    const float* b1b  = (const float*)d_in[5];
    const float* W2a  = (const float*)d_in[6];
    const float* b2a  = (const float*)d_in[7];
    const float* W2b  = (const float*)d_in[8];
    const float* b2b  = (const float*)d_in[9];
    const float* eps1 = (const float*)d_in[10];
    const float* eps2 = (const float*)d_in[11];
    const int nE = in_sizes[1] / 2;
    const int* srcv = ei;
    const int* dstv = ei + nE;

    // ---- compact workspace layout (~215 MB) ----
    char* ws = (char*)d_ws;
    int*    off    = (int*)(ws);                        // 100001 ints (400004 B)
    int*    part   = (int*)(ws + 458752);               // 196 ints (scan partials)
    int*    deg    = (int*)(ws + 524288);               // 100000 ints (destroyed by fill)
    int*    csr    = (int*)(ws + 1048576);              // 1.6M ints
    ushort* Wt1a   = (ushort*)(ws + 8388608);           // [512][256] bf16
    ushort* Wt1b   = Wt1a + 512 * 256;                  // [512][512]
    ushort* Wt2a   = Wt1b + 512 * 512;                  // [512][512]
    ushort* Wt2b   = Wt2a + 512 * 512;                  // [256][512]
    char*   P      = ws + 10485760;                     // 102,400,000 B slot
    char*   Q      = ws + 10485760 + 102400000;         // 102,400,000 B slot
    uint8_t* x8    = (uint8_t*)P;  // [100000,256] fp8 (dead before h1 written)
    ushort* agg1b  = (ushort*)Q;   // [100000,256] bf16 (dead before h2f8 written)
    ushort* h1     = (ushort*)P;   // [100000,512] bf16
    uint8_t* h2f8  = (uint8_t*)Q;  // [100000,512] fp8
    ushort* agg2b  = (ushort*)P;   // [100000,512] bf16 (h1 dead)
    ushort* h3     = (ushort*)Q;   // [100000,512] bf16 (h2f8 dead)

    // ---- CSR build (parallel scan) + weight/x prep (fused) ----
    const int cb = (nE + 255) / 256;
    const int castb = (NN * NFEATD / 8 + 255) / 256;
    zero_i32<<<(NN + 255) / 256, 256, 0, stream>>>(deg, NN);
    fused_misc<<<cb + 3072 + castb, 256, 0, stream>>>(dstv, deg, nE, cb,
                                                      W1a, W1b, W2a, W2b,
                                                      Wt1a, Wt1b, Wt2a, Wt2b,
                                                      x, x8, NN * NFEATD);
    const int nsb = (NN + 511) / 512;                // 196 scan blocks
    scan_part<<<nsb, 256, 0, stream>>>(deg, part, NN);
    scan_mid<<<1, 256, 0, stream>>>(part, off + NN, nsb);
    scan_apply<<<nsb, 256, 0, stream>>>(deg, part, off, NN);
    fill_csr2<<<cb, 256, 0, stream>>>(srcv, dstv, off, deg, csr, nE);

    // ---- layer 1: agg -> MLP ----
    gather256f8<<<(NN * 64) / 256, 256, 0, stream>>>(x8, off, csr, eps1, agg1b);
    const int nrow = (NN + 127) / 128;               // 782 row panels
    gemm_bt<<<nrow * (NHIDD / 256), 512, 0, stream>>>(agg1b, Wt1a, b1a, nullptr, nullptr, h1, NN, NHIDD, NFEATD, 1);
    gemm_bt<<<nrow * (NHIDD / 256), 512, 0, stream>>>(h1, Wt1b, b1b, nullptr, h2f8, nullptr, NN, NHIDD, NHIDD, 1);

    // ---- layer 2: agg -> MLP ----
    gather512f8<<<(NN * 64) / 256, 256, 0, stream>>>(h2f8, off, csr, eps2, agg2b);
    gemm_bt<<<nrow * (NHIDD / 256), 512, 0, stream>>>(agg2b, Wt2a, b2a, nullptr, nullptr, h3, NN, NHIDD, NHIDD, 1);
    gemm_bt<<<nrow * (NCLASSD / 256), 512, 0, stream>>>(h3, Wt2b, b2b, (float*)d_out, nullptr, nullptr, NN, NCLASSD, NHIDD, 0);
}